// Round 7
// baseline (421.927 us; speedup 1.0000x reference)
//
#include <hip/hip_runtime.h>
#include <hip/hip_fp16.h>

#define NN 100000
#define NE 1600000
#define DF 50
#define NC 47
#define DP 64     // padded feature dim; fp16 row = 128 B = 8 x 16B chunks
#define ZROW NN   // index of the all-zero row (for masked-out gathers)

static_assert(NN % 16 == 0, "grid exactness");
static_assert(NE % 4 == 0, "int4 edge loads");

typedef _Float16 half8 __attribute__((ext_vector_type(8)));
typedef float float4v __attribute__((ext_vector_type(4)));

__global__ void deg_kernel(const int4* __restrict__ dst4, unsigned* __restrict__ deg, int E4) {
    int t = blockIdx.x * blockDim.x + threadIdx.x;
    if (t < E4) {
        int4 q = dst4[t];
        atomicAdd(&deg[q.x], 1u);
        atomicAdd(&deg[q.y], 1u);
        atomicAdd(&deg[q.z], 1u);
        atomicAdd(&deg[q.w], 1u);
    }
}

// Per-node: dinv/selfw; CSR row allocation via wave scan + one atomic per wave.
__global__ void alloc_kernel(const unsigned* __restrict__ deg, float* __restrict__ dinv,
                             float* __restrict__ selfw, unsigned* __restrict__ rowStart,
                             unsigned* __restrict__ cursor, unsigned* __restrict__ total, int N) {
    int n = blockIdx.x * blockDim.x + threadIdx.x;
    int lane = threadIdx.x & 63;
    unsigned d = (n < N) ? deg[n] : 0u;
    unsigned s = d;
    #pragma unroll
    for (int off = 1; off < 64; off <<= 1) {
        unsigned t = __shfl_up(s, off);
        if (lane >= off) s += t;
    }
    unsigned waveSum = __shfl(s, 63);
    unsigned base = 0;
    if (lane == 63) base = atomicAdd(total, waveSum);
    base = __shfl(base, 63);
    if (n < N) {
        unsigned rs = base + s - d;
        rowStart[n] = rs;
        cursor[n]   = rs;
        float dd = 1.0f + (float)d;
        float r = rsqrtf(dd);
        dinv[n] = r;
        selfw[n] = r * r;
    }
}

// col-only CSR fill: 4 edges/thread, 4 outstanding slot-atomics, 4B scattered stores.
__global__ void fill_kernel(const int4* __restrict__ src4, const int4* __restrict__ dst4,
                            unsigned* __restrict__ cursor, int* __restrict__ cols, int E4) {
    int t = blockIdx.x * blockDim.x + threadIdx.x;
    if (t >= E4) return;
    int4 s = src4[t];
    int4 q = dst4[t];
    unsigned p0 = atomicAdd(&cursor[q.x], 1u);
    unsigned p1 = atomicAdd(&cursor[q.y], 1u);
    unsigned p2 = atomicAdd(&cursor[q.z], 1u);
    unsigned p3 = atomicAdd(&cursor[q.w], 1u);
    cols[p0] = s.x;
    cols[p1] = s.y;
    cols[p2] = s.z;
    cols[p3] = s.w;
}

// feat [NN,50] fp32 -> featp [NN+1,64] fp16, PRE-SCALED by dinv[n]; row NN = zeros.
__global__ void pad_kernel(const float* __restrict__ f, const float* __restrict__ dinv,
                           float4* __restrict__ fp, int total8) {
    int t = blockIdx.x * blockDim.x + threadIdx.x;
    if (t >= total8) return;
    int n = t >> 3, c = t & 7;
    float sc = (n < NN) ? dinv[n] : 0.f;
    float v[8];
    #pragma unroll
    for (int i = 0; i < 8; ++i) {
        int e = c * 8 + i;
        v[i] = (n < NN && e < DF) ? sc * f[n * DF + e] : 0.f;
    }
    float4 ov;
    __half2* op = (__half2*)&ov;
    #pragma unroll
    for (int i = 0; i < 4; ++i) op[i] = __floats2half2_rn(v[2 * i], v[2 * i + 1]);
    fp[t] = ov;
}

// One wave per TWO dst nodes. Pure unweighted gather-sum of pre-scaled rows;
// self term = own row; epilogue multiplies by scaleArr[nd] (selfw for hop1, dinv for hop2).
__global__ __launch_bounds__(256) void hop_kernel(const _Float16* __restrict__ h,
    const int* __restrict__ cols, const unsigned* __restrict__ rowStart,
    const unsigned* __restrict__ deg, const float* __restrict__ scaleArr,
    _Float16* __restrict__ hn) {

    int lane = threadIdx.x & 63;
    int wid  = (int)((blockIdx.x * blockDim.x + threadIdx.x) >> 6);
    int half = lane >> 5;          // which node this lane serves
    int g    = (lane >> 3) & 3;    // edge sub-slot 0..3
    int qid  = lane & 7;           // 16B chunk within the 128B row

    int nd = 2 * wid + half;
    unsigned rs = rowStart[nd];
    unsigned d  = deg[nd];
    unsigned dmax = max(__shfl(d, 0), __shfl(d, 32));

    float acc[8] = {0.f, 0.f, 0.f, 0.f, 0.f, 0.f, 0.f, 0.f};

    for (unsigned j0 = 0; j0 < dmax; j0 += 16u) {
        #pragma unroll
        for (int u = 0; u < 4; ++u) {
            unsigned j = j0 + (unsigned)(g + 4 * u);
            unsigned idx = min(rs + j, (unsigned)(NE - 1));   // safe load
            int c = cols[idx];                                // 8 lanes same addr -> broadcast
            c = (j < d) ? c : ZROW;                           // masked edges read the zero row
            half8 v = *(const half8*)(h + (long)c * DP + qid * 8);
            #pragma unroll
            for (int i = 0; i < 8; ++i) acc[i] += (float)v[i];
        }
    }

    // combine the 4 edge sub-slots within each half (lanes sharing qid)
    #pragma unroll
    for (int i = 0; i < 8; ++i) {
        acc[i] += __shfl_xor(acc[i], 8);
        acc[i] += __shfl_xor(acc[i], 16);
    }

    // + own (pre-scaled) row, then scale and pack
    float s = scaleArr[nd];
    half8 hv = *(const half8*)(h + (long)nd * DP + qid * 8);
    half8 ov;
    #pragma unroll
    for (int i = 0; i < 8; ++i)
        ov[i] = (_Float16)(s * (acc[i] + (float)hv[i]));
    if ((lane & 24) == 0)
        *(half8*)(hn + (long)nd * DP + qid * 8) = ov;
}

// out[100000,47] = h2[100000,64(fp16)] @ Wp^T + b  via mfma_f32_16x16x32_f16.
__global__ __launch_bounds__(256) void fc_kernel(const _Float16* __restrict__ h2,
    const float* __restrict__ W, const float* __restrict__ b,
    float* __restrict__ out, int MT) {

    __shared__ _Float16 sW[48 * 72];   // Wp[n][k], row stride 72 halves (bank-conflict pad)
    __shared__ float sB[48];

    for (int i = threadIdx.x; i < 48 * 64; i += 256) {
        int n = i >> 6, k = i & 63;
        float v = (n < NC && k < DF) ? W[n * DF + k] : 0.f;
        sW[n * 72 + k] = (_Float16)v;
    }
    if (threadIdx.x < 48) sB[threadIdx.x] = (threadIdx.x < NC) ? b[threadIdx.x] : 0.f;
    __syncthreads();

    int lane = threadIdx.x & 63;
    int wid  = (int)((blockIdx.x * blockDim.x + threadIdx.x) >> 6);
    if (wid >= MT) return;

    int m0 = wid * 16;
    int am = lane & 15;            // A row within tile / B col (n within tile)
    int aq = lane >> 4;            // k-quad: k = aq*8 + j

    const half8* arow = (const half8*)(h2 + (long)(m0 + am) * DP);
    half8 a0 = arow[aq];
    half8 a1 = arow[aq + 4];
    int row = aq * 4;

    #pragma unroll
    for (int t = 0; t < 3; ++t) {
        int n = t * 16 + am;
        const half8* brow = (const half8*)(sW + n * 72);
        half8 b0 = brow[aq];
        half8 b1 = brow[aq + 4];
        float4v c = {0.f, 0.f, 0.f, 0.f};
        c = __builtin_amdgcn_mfma_f32_16x16x32_f16(a0, b0, c, 0, 0, 0);
        c = __builtin_amdgcn_mfma_f32_16x16x32_f16(a1, b1, c, 0, 0, 0);
        if (n < NC) {
            float bn = sB[n];
            #pragma unroll
            for (int r = 0; r < 4; ++r)
                out[(long)(m0 + row + r) * NC + n] = c[r] + bn;
        }
    }
}

extern "C" void kernel_launch(void* const* d_in, const int* in_sizes, int n_in,
                              void* d_out, int out_size, void* d_ws, size_t ws_size,
                              hipStream_t stream) {
    const float* feat = (const float*)d_in[0];
    const float* W    = (const float*)d_in[1];
    const float* b    = (const float*)d_in[2];
    const int*  esrc  = (const int*)d_in[3];
    const int*  edst  = (const int*)d_in[4];
    float* out = (float*)d_out;

    char* ws = (char*)d_ws;
    unsigned* deg      = (unsigned*)ws; ws += NN * sizeof(unsigned);
    unsigned* total    = (unsigned*)ws; ws += 4 * sizeof(unsigned);   // memset with deg
    unsigned* cursor   = (unsigned*)ws; ws += NN * sizeof(unsigned);
    unsigned* rowStart = (unsigned*)ws; ws += NN * sizeof(unsigned);
    float*    dinv     = (float*)ws;    ws += NN * sizeof(float);
    float*    selfw    = (float*)ws;    ws += NN * sizeof(float);
    int*      cols     = (int*)ws;      ws += (size_t)NE * sizeof(int);
    _Float16* featp    = (_Float16*)ws; ws += (size_t)(NN + 1) * DP * sizeof(_Float16);
    _Float16* h1p      = (_Float16*)ws; ws += (size_t)(NN + 1) * DP * sizeof(_Float16);
    _Float16* h2p      = (_Float16*)ws;

    hipMemsetAsync(deg, 0, (NN + 4) * sizeof(unsigned), stream);
    hipMemsetAsync(h1p + (size_t)ZROW * DP, 0, DP * sizeof(_Float16), stream);  // zero row of h1

    deg_kernel<<<(NE / 4 + 255) / 256, 256, 0, stream>>>((const int4*)edst, deg, NE / 4);
    alloc_kernel<<<(NN + 255) / 256, 256, 0, stream>>>(deg, dinv, selfw, rowStart, cursor, total, NN);
    fill_kernel<<<(NE / 4 + 255) / 256, 256, 0, stream>>>((const int4*)esrc, (const int4*)edst,
                                                          cursor, cols, NE / 4);
    pad_kernel<<<((NN + 1) * 8 + 255) / 256, 256, 0, stream>>>(feat, dinv, (float4*)featp, (NN + 1) * 8);

    const int hop_blocks = NN / 8;   // 2 nodes/wave, 4 waves/block, exact
    hop_kernel<<<hop_blocks, 256, 0, stream>>>(featp, cols, rowStart, deg, selfw, h1p);
    hop_kernel<<<hop_blocks, 256, 0, stream>>>(h1p, cols, rowStart, deg, dinv, h2p);

    const int MT = NN / 16;          // 6250 M-tiles
    fc_kernel<<<(MT + 3) / 4, 256, 0, stream>>>(h2p, W, b, out, MT);
}

// Round 8
// 397.321 us; speedup vs baseline: 1.0619x; 1.0619x over previous
//
#include <hip/hip_runtime.h>
#include <hip/hip_fp16.h>

#define NN 100000
#define NE 1600000
#define DF 50
#define NC 47
#define DP 64     // padded feature dim; fp16 row = 128 B = 8 x 16B chunks
#define ZROW NN   // index of the all-zero row (for masked-out gathers)

static_assert(NN % 16 == 0, "grid exactness");
static_assert(NE % 4 == 0, "int4 edge loads");

typedef _Float16 half8 __attribute__((ext_vector_type(8)));
typedef float float4v __attribute__((ext_vector_type(4)));

__global__ void deg_kernel(const int4* __restrict__ dst4, unsigned* __restrict__ deg, int E4) {
    int t = blockIdx.x * blockDim.x + threadIdx.x;
    if (t < E4) {
        int4 q = dst4[t];
        atomicAdd(&deg[q.x], 1u);
        atomicAdd(&deg[q.y], 1u);
        atomicAdd(&deg[q.z], 1u);
        atomicAdd(&deg[q.w], 1u);
    }
}

// Per-node: dinv/selfw; CSR row allocation via wave scan + one atomic per wave.
__global__ void alloc_kernel(const unsigned* __restrict__ deg, float* __restrict__ dinv,
                             float* __restrict__ selfw, unsigned* __restrict__ rowStart,
                             unsigned* __restrict__ cursor, unsigned* __restrict__ total, int N) {
    int n = blockIdx.x * blockDim.x + threadIdx.x;
    int lane = threadIdx.x & 63;
    unsigned d = (n < N) ? deg[n] : 0u;
    unsigned s = d;
    #pragma unroll
    for (int off = 1; off < 64; off <<= 1) {
        unsigned t = __shfl_up(s, off);
        if (lane >= off) s += t;
    }
    unsigned waveSum = __shfl(s, 63);
    unsigned base = 0;
    if (lane == 63) base = atomicAdd(total, waveSum);
    base = __shfl(base, 63);
    if (n < N) {
        unsigned rs = base + s - d;
        rowStart[n] = rs;
        cursor[n]   = rs;
        float dd = 1.0f + (float)d;
        float r = rsqrtf(dd);
        dinv[n] = r;
        selfw[n] = r * r;
    }
}

// Phase 1: slot assignment only — 4 cursor atomics in flight, COALESCED uint4 result store.
__global__ void slot_kernel(const int4* __restrict__ dst4, unsigned* __restrict__ cursor,
                            uint4* __restrict__ pslots, int E4) {
    int t = blockIdx.x * blockDim.x + threadIdx.x;
    if (t >= E4) return;
    int4 q = dst4[t];
    uint4 p;
    p.x = atomicAdd(&cursor[q.x], 1u);
    p.y = atomicAdd(&cursor[q.y], 1u);
    p.z = atomicAdd(&cursor[q.z], 1u);
    p.w = atomicAdd(&cursor[q.w], 1u);
    pslots[t] = p;
}

// Phase 2: pure scatter — coalesced loads, 4 non-temporal 4B stores, no dependents.
__global__ void scat_kernel(const int4* __restrict__ src4, const uint4* __restrict__ pslots,
                            int* __restrict__ cols, int E4) {
    int t = blockIdx.x * blockDim.x + threadIdx.x;
    if (t >= E4) return;
    int4  s = src4[t];
    uint4 p = pslots[t];
    __builtin_nontemporal_store(s.x, &cols[p.x]);
    __builtin_nontemporal_store(s.y, &cols[p.y]);
    __builtin_nontemporal_store(s.z, &cols[p.z]);
    __builtin_nontemporal_store(s.w, &cols[p.w]);
}

// feat [NN,50] fp32 -> featp [NN+1,64] fp16, PRE-SCALED by dinv[n]; row NN = zeros.
__global__ void pad_kernel(const float* __restrict__ f, const float* __restrict__ dinv,
                           float4* __restrict__ fp, int total8) {
    int t = blockIdx.x * blockDim.x + threadIdx.x;
    if (t >= total8) return;
    int n = t >> 3, c = t & 7;
    float sc = (n < NN) ? dinv[n] : 0.f;
    float v[8];
    #pragma unroll
    for (int i = 0; i < 8; ++i) {
        int e = c * 8 + i;
        v[i] = (n < NN && e < DF) ? sc * f[n * DF + e] : 0.f;
    }
    float4 ov;
    __half2* op = (__half2*)&ov;
    #pragma unroll
    for (int i = 0; i < 4; ++i) op[i] = __floats2half2_rn(v[2 * i], v[2 * i + 1]);
    fp[t] = ov;
}

// One wave per TWO dst nodes. Pure unweighted gather-sum of pre-scaled rows;
// self term = own row; epilogue multiplies by scaleArr[nd] (selfw for hop1, dinv for hop2).
__global__ __launch_bounds__(256) void hop_kernel(const _Float16* __restrict__ h,
    const int* __restrict__ cols, const unsigned* __restrict__ rowStart,
    const unsigned* __restrict__ deg, const float* __restrict__ scaleArr,
    _Float16* __restrict__ hn) {

    int lane = threadIdx.x & 63;
    int wid  = (int)((blockIdx.x * blockDim.x + threadIdx.x) >> 6);
    int half = lane >> 5;          // which node this lane serves
    int g    = (lane >> 3) & 3;    // edge sub-slot 0..3
    int qid  = lane & 7;           // 16B chunk within the 128B row

    int nd = 2 * wid + half;
    unsigned rs = rowStart[nd];
    unsigned d  = deg[nd];
    unsigned dmax = max(__shfl(d, 0), __shfl(d, 32));

    float acc[8] = {0.f, 0.f, 0.f, 0.f, 0.f, 0.f, 0.f, 0.f};

    for (unsigned j0 = 0; j0 < dmax; j0 += 16u) {
        #pragma unroll
        for (int u = 0; u < 4; ++u) {
            unsigned j = j0 + (unsigned)(g + 4 * u);
            unsigned idx = min(rs + j, (unsigned)(NE - 1));   // safe load
            int c = cols[idx];                                // 8 lanes same addr -> broadcast
            c = (j < d) ? c : ZROW;                           // masked edges read the zero row
            half8 v = *(const half8*)(h + (long)c * DP + qid * 8);
            #pragma unroll
            for (int i = 0; i < 8; ++i) acc[i] += (float)v[i];
        }
    }

    // combine the 4 edge sub-slots within each half (lanes sharing qid)
    #pragma unroll
    for (int i = 0; i < 8; ++i) {
        acc[i] += __shfl_xor(acc[i], 8);
        acc[i] += __shfl_xor(acc[i], 16);
    }

    // + own (pre-scaled) row, then scale and pack
    float s = scaleArr[nd];
    half8 hv = *(const half8*)(h + (long)nd * DP + qid * 8);
    half8 ov;
    #pragma unroll
    for (int i = 0; i < 8; ++i)
        ov[i] = (_Float16)(s * (acc[i] + (float)hv[i]));
    if ((lane & 24) == 0)
        *(half8*)(hn + (long)nd * DP + qid * 8) = ov;
}

// out[100000,47] = h2[100000,64(fp16)] @ Wp^T + b  via mfma_f32_16x16x32_f16.
__global__ __launch_bounds__(256) void fc_kernel(const _Float16* __restrict__ h2,
    const float* __restrict__ W, const float* __restrict__ b,
    float* __restrict__ out, int MT) {

    __shared__ _Float16 sW[48 * 72];   // Wp[n][k], row stride 72 halves (bank-conflict pad)
    __shared__ float sB[48];

    for (int i = threadIdx.x; i < 48 * 64; i += 256) {
        int n = i >> 6, k = i & 63;
        float v = (n < NC && k < DF) ? W[n * DF + k] : 0.f;
        sW[n * 72 + k] = (_Float16)v;
    }
    if (threadIdx.x < 48) sB[threadIdx.x] = (threadIdx.x < NC) ? b[threadIdx.x] : 0.f;
    __syncthreads();

    int lane = threadIdx.x & 63;
    int wid  = (int)((blockIdx.x * blockDim.x + threadIdx.x) >> 6);
    if (wid >= MT) return;

    int m0 = wid * 16;
    int am = lane & 15;            // A row within tile / B col (n within tile)
    int aq = lane >> 4;            // k-quad: k = aq*8 + j

    const half8* arow = (const half8*)(h2 + (long)(m0 + am) * DP);
    half8 a0 = arow[aq];
    half8 a1 = arow[aq + 4];
    int row = aq * 4;

    #pragma unroll
    for (int t = 0; t < 3; ++t) {
        int n = t * 16 + am;
        const half8* brow = (const half8*)(sW + n * 72);
        half8 b0 = brow[aq];
        half8 b1 = brow[aq + 4];
        float4v c = {0.f, 0.f, 0.f, 0.f};
        c = __builtin_amdgcn_mfma_f32_16x16x32_f16(a0, b0, c, 0, 0, 0);
        c = __builtin_amdgcn_mfma_f32_16x16x32_f16(a1, b1, c, 0, 0, 0);
        if (n < NC) {
            float bn = sB[n];
            #pragma unroll
            for (int r = 0; r < 4; ++r)
                out[(long)(m0 + row + r) * NC + n] = c[r] + bn;
        }
    }
}

extern "C" void kernel_launch(void* const* d_in, const int* in_sizes, int n_in,
                              void* d_out, int out_size, void* d_ws, size_t ws_size,
                              hipStream_t stream) {
    const float* feat = (const float*)d_in[0];
    const float* W    = (const float*)d_in[1];
    const float* b    = (const float*)d_in[2];
    const int*  esrc  = (const int*)d_in[3];
    const int*  edst  = (const int*)d_in[4];
    float* out = (float*)d_out;

    char* ws = (char*)d_ws;
    unsigned* deg      = (unsigned*)ws; ws += NN * sizeof(unsigned);
    unsigned* total    = (unsigned*)ws; ws += 4 * sizeof(unsigned);   // memset with deg
    unsigned* cursor   = (unsigned*)ws; ws += NN * sizeof(unsigned);
    unsigned* rowStart = (unsigned*)ws; ws += NN * sizeof(unsigned);
    float*    dinv     = (float*)ws;    ws += NN * sizeof(float);
    float*    selfw    = (float*)ws;    ws += NN * sizeof(float);
    unsigned* pslots   = (unsigned*)ws; ws += (size_t)NE * sizeof(unsigned);
    int*      cols     = (int*)ws;      ws += (size_t)NE * sizeof(int);
    _Float16* featp    = (_Float16*)ws; ws += (size_t)(NN + 1) * DP * sizeof(_Float16);
    _Float16* h1p      = (_Float16*)ws; ws += (size_t)(NN + 1) * DP * sizeof(_Float16);
    _Float16* h2p      = (_Float16*)ws;

    hipMemsetAsync(deg, 0, (NN + 4) * sizeof(unsigned), stream);
    hipMemsetAsync(h1p + (size_t)ZROW * DP, 0, DP * sizeof(_Float16), stream);  // zero row of h1

    deg_kernel<<<(NE / 4 + 255) / 256, 256, 0, stream>>>((const int4*)edst, deg, NE / 4);
    alloc_kernel<<<(NN + 255) / 256, 256, 0, stream>>>(deg, dinv, selfw, rowStart, cursor, total, NN);
    slot_kernel<<<(NE / 4 + 255) / 256, 256, 0, stream>>>((const int4*)edst, cursor,
                                                          (uint4*)pslots, NE / 4);
    scat_kernel<<<(NE / 4 + 255) / 256, 256, 0, stream>>>((const int4*)esrc, (const uint4*)pslots,
                                                          cols, NE / 4);
    pad_kernel<<<((NN + 1) * 8 + 255) / 256, 256, 0, stream>>>(feat, dinv, (float4*)featp, (NN + 1) * 8);

    const int hop_blocks = NN / 8;   // 2 nodes/wave, 4 waves/block, exact
    hop_kernel<<<hop_blocks, 256, 0, stream>>>(featp, cols, rowStart, deg, selfw, h1p);
    hop_kernel<<<hop_blocks, 256, 0, stream>>>(h1p, cols, rowStart, deg, dinv, h2p);

    const int MT = NN / 16;          // 6250 M-tiles
    fc_kernel<<<(MT + 3) / 4, 256, 0, stream>>>(h2p, W, b, out, MT);
}

// Round 9
// 328.444 us; speedup vs baseline: 1.2846x; 1.2097x over previous
//
#include <hip/hip_runtime.h>
#include <hip/hip_fp16.h>

#define NN 100000
#define NE 1600000
#define DF 50
#define NC 47
#define DP 64     // padded feature dim; fp16 row = 128 B = 8 x 16B chunks
#define ZROW NN   // index of the all-zero row (for masked-out gathers)

static_assert(NN % 16 == 0, "grid exactness");
static_assert(NE % 4 == 0, "int4 edge loads");

typedef _Float16 half8 __attribute__((ext_vector_type(8)));
typedef float float4v __attribute__((ext_vector_type(4)));

// Phase 1: counting + slot assignment in ONE pass. cursor starts at 0; the
// returned value is the in-node position, the final cursor value is the degree.
__global__ void slot_kernel(const int4* __restrict__ dst4, unsigned* __restrict__ cursor,
                            uint4* __restrict__ pslots, int E4) {
    int t = blockIdx.x * blockDim.x + threadIdx.x;
    if (t >= E4) return;
    int4 q = dst4[t];
    uint4 p;
    p.x = atomicAdd(&cursor[q.x], 1u);
    p.y = atomicAdd(&cursor[q.y], 1u);
    p.z = atomicAdd(&cursor[q.z], 1u);
    p.w = atomicAdd(&cursor[q.w], 1u);
    pslots[t] = p;
}

// Per-node: dinv/selfw; CSR row allocation via wave scan + one atomic per wave.
// deg comes from the final cursor values (written by slot_kernel).
__global__ void alloc_kernel(const unsigned* __restrict__ degArr, float* __restrict__ dinv,
                             float* __restrict__ selfw, unsigned* __restrict__ rowStart,
                             unsigned* __restrict__ total, int N) {
    int n = blockIdx.x * blockDim.x + threadIdx.x;
    int lane = threadIdx.x & 63;
    unsigned d = (n < N) ? degArr[n] : 0u;
    unsigned s = d;
    #pragma unroll
    for (int off = 1; off < 64; off <<= 1) {
        unsigned t = __shfl_up(s, off);
        if (lane >= off) s += t;
    }
    unsigned waveSum = __shfl(s, 63);
    unsigned base = 0;
    if (lane == 63) base = atomicAdd(total, waveSum);
    base = __shfl(base, 63);
    if (n < N) {
        rowStart[n] = base + s - d;
        float dd = 1.0f + (float)d;
        float r = rsqrtf(dd);
        dinv[n] = r;
        selfw[n] = r * r;
    }
}

#define SCAT_B ((NE / 4 + 255) / 256)
#define PAD_B  (((NN + 1) * 8 + 255) / 256)

// Grid-split: blocks [0,SCAT_B) scatter cols; blocks [SCAT_B,..) build featp
// (pre-scaled by dinv, fp16, zero-padded; row NN = zeros) and zero h1p's ZROW.
__global__ void scatpad_kernel(const int4* __restrict__ src4, const int4* __restrict__ dst4,
                               const uint4* __restrict__ pslots,
                               const unsigned* __restrict__ rowStart,
                               int* __restrict__ cols,
                               const float* __restrict__ f, const float* __restrict__ dinv,
                               float4* __restrict__ fp, float4* __restrict__ h1p4) {
    if (blockIdx.x < SCAT_B) {
        int t = blockIdx.x * blockDim.x + threadIdx.x;
        if (t >= NE / 4) return;
        int4  s = src4[t];
        int4  q = dst4[t];
        uint4 p = pslots[t];
        unsigned i0 = rowStart[q.x] + p.x;
        unsigned i1 = rowStart[q.y] + p.y;
        unsigned i2 = rowStart[q.z] + p.z;
        unsigned i3 = rowStart[q.w] + p.w;
        __builtin_nontemporal_store(s.x, &cols[i0]);
        __builtin_nontemporal_store(s.y, &cols[i1]);
        __builtin_nontemporal_store(s.z, &cols[i2]);
        __builtin_nontemporal_store(s.w, &cols[i3]);
    } else {
        int t = (blockIdx.x - SCAT_B) * blockDim.x + threadIdx.x;
        if (t >= (NN + 1) * 8) return;
        int n = t >> 3, c = t & 7;
        float sc = (n < NN) ? dinv[n] : 0.f;
        float v[8];
        #pragma unroll
        for (int i = 0; i < 8; ++i) {
            int e = c * 8 + i;
            v[i] = (n < NN && e < DF) ? sc * f[n * DF + e] : 0.f;
        }
        float4 ov;
        __half2* op = (__half2*)&ov;
        #pragma unroll
        for (int i = 0; i < 4; ++i) op[i] = __floats2half2_rn(v[2 * i], v[2 * i + 1]);
        fp[t] = ov;
        if (n == NN) h1p4[t] = make_float4(0.f, 0.f, 0.f, 0.f);  // zero row of h1
    }
}

// One wave per TWO dst nodes. Pure unweighted gather-sum of pre-scaled rows,
// 8 gathers in flight (32 edge-slots per body). Epilogue scales by scaleArr[nd].
__global__ __launch_bounds__(256) void hop_kernel(const _Float16* __restrict__ h,
    const int* __restrict__ cols, const unsigned* __restrict__ rowStart,
    const unsigned* __restrict__ deg, const float* __restrict__ scaleArr,
    _Float16* __restrict__ hn) {

    int lane = threadIdx.x & 63;
    int wid  = (int)((blockIdx.x * blockDim.x + threadIdx.x) >> 6);
    int half = lane >> 5;          // which node this lane serves
    int g    = (lane >> 3) & 3;    // edge sub-slot 0..3
    int qid  = lane & 7;           // 16B chunk within the 128B row

    int nd = 2 * wid + half;
    unsigned rs = rowStart[nd];
    unsigned d  = deg[nd];
    unsigned dmax = max(__shfl(d, 0), __shfl(d, 32));

    float acc[8] = {0.f, 0.f, 0.f, 0.f, 0.f, 0.f, 0.f, 0.f};

    for (unsigned j0 = 0; j0 < dmax; j0 += 32u) {
        #pragma unroll
        for (int u = 0; u < 8; ++u) {
            unsigned j = j0 + (unsigned)(g + 4 * u);
            unsigned idx = min(rs + j, (unsigned)(NE - 1));   // safe load
            int c = cols[idx];                                // 8 lanes same addr -> broadcast
            c = (j < d) ? c : ZROW;                           // masked edges read the zero row
            half8 v = *(const half8*)(h + (unsigned)c * DP + qid * 8);
            #pragma unroll
            for (int i = 0; i < 8; ++i) acc[i] += (float)v[i];
        }
    }

    // combine the 4 edge sub-slots within each half (lanes sharing qid)
    #pragma unroll
    for (int i = 0; i < 8; ++i) {
        acc[i] += __shfl_xor(acc[i], 8);
        acc[i] += __shfl_xor(acc[i], 16);
    }

    // + own (pre-scaled) row, then scale and pack
    float s = scaleArr[nd];
    half8 hv = *(const half8*)(h + (unsigned)nd * DP + qid * 8);
    half8 ov;
    #pragma unroll
    for (int i = 0; i < 8; ++i)
        ov[i] = (_Float16)(s * (acc[i] + (float)hv[i]));
    if ((lane & 24) == 0)
        *(half8*)(hn + (unsigned)nd * DP + qid * 8) = ov;
}

// out[100000,47] = h2[100000,64(fp16)] @ Wp^T + b  via mfma_f32_16x16x32_f16.
__global__ __launch_bounds__(256) void fc_kernel(const _Float16* __restrict__ h2,
    const float* __restrict__ W, const float* __restrict__ b,
    float* __restrict__ out, int MT) {

    __shared__ _Float16 sW[48 * 72];   // Wp[n][k], row stride 72 halves (bank-conflict pad)
    __shared__ float sB[48];

    for (int i = threadIdx.x; i < 48 * 64; i += 256) {
        int n = i >> 6, k = i & 63;
        float v = (n < NC && k < DF) ? W[n * DF + k] : 0.f;
        sW[n * 72 + k] = (_Float16)v;
    }
    if (threadIdx.x < 48) sB[threadIdx.x] = (threadIdx.x < NC) ? b[threadIdx.x] : 0.f;
    __syncthreads();

    int lane = threadIdx.x & 63;
    int wid  = (int)((blockIdx.x * blockDim.x + threadIdx.x) >> 6);
    if (wid >= MT) return;

    int m0 = wid * 16;
    int am = lane & 15;            // A row within tile / B col (n within tile)
    int aq = lane >> 4;            // k-quad: k = aq*8 + j

    const half8* arow = (const half8*)(h2 + (long)(m0 + am) * DP);
    half8 a0 = arow[aq];
    half8 a1 = arow[aq + 4];
    int row = aq * 4;

    #pragma unroll
    for (int t = 0; t < 3; ++t) {
        int n = t * 16 + am;
        const half8* brow = (const half8*)(sW + n * 72);
        half8 b0 = brow[aq];
        half8 b1 = brow[aq + 4];
        float4v c = {0.f, 0.f, 0.f, 0.f};
        c = __builtin_amdgcn_mfma_f32_16x16x32_f16(a0, b0, c, 0, 0, 0);
        c = __builtin_amdgcn_mfma_f32_16x16x32_f16(a1, b1, c, 0, 0, 0);
        if (n < NC) {
            float bn = sB[n];
            #pragma unroll
            for (int r = 0; r < 4; ++r)
                out[(long)(m0 + row + r) * NC + n] = c[r] + bn;
        }
    }
}

extern "C" void kernel_launch(void* const* d_in, const int* in_sizes, int n_in,
                              void* d_out, int out_size, void* d_ws, size_t ws_size,
                              hipStream_t stream) {
    const float* feat = (const float*)d_in[0];
    const float* W    = (const float*)d_in[1];
    const float* b    = (const float*)d_in[2];
    const int*  esrc  = (const int*)d_in[3];
    const int*  edst  = (const int*)d_in[4];
    float* out = (float*)d_out;

    char* ws = (char*)d_ws;
    unsigned* cursor   = (unsigned*)ws; ws += NN * sizeof(unsigned);   // becomes deg after slot
    unsigned* total    = (unsigned*)ws; ws += 4 * sizeof(unsigned);    // memset with cursor
    unsigned* rowStart = (unsigned*)ws; ws += NN * sizeof(unsigned);
    float*    dinv     = (float*)ws;    ws += NN * sizeof(float);
    float*    selfw    = (float*)ws;    ws += NN * sizeof(float);
    unsigned* pslots   = (unsigned*)ws; ws += (size_t)NE * sizeof(unsigned);
    int*      cols     = (int*)ws;      ws += (size_t)NE * sizeof(int);
    _Float16* featp    = (_Float16*)ws; ws += (size_t)(NN + 1) * DP * sizeof(_Float16);
    _Float16* h1p      = (_Float16*)ws; ws += (size_t)(NN + 1) * DP * sizeof(_Float16);
    _Float16* h2p      = (_Float16*)ws;

    hipMemsetAsync(cursor, 0, (NN + 4) * sizeof(unsigned), stream);

    slot_kernel<<<(NE / 4 + 255) / 256, 256, 0, stream>>>((const int4*)edst, cursor,
                                                          (uint4*)pslots, NE / 4);
    alloc_kernel<<<(NN + 255) / 256, 256, 0, stream>>>(cursor, dinv, selfw, rowStart, total, NN);
    scatpad_kernel<<<SCAT_B + PAD_B, 256, 0, stream>>>((const int4*)esrc, (const int4*)edst,
                                                       (const uint4*)pslots, rowStart, cols,
                                                       feat, dinv, (float4*)featp, (float4*)h1p);

    const int hop_blocks = NN / 8;   // 2 nodes/wave, 4 waves/block, exact
    hop_kernel<<<hop_blocks, 256, 0, stream>>>(featp, cols, rowStart, cursor, selfw, h1p);
    hop_kernel<<<hop_blocks, 256, 0, stream>>>(h1p, cols, rowStart, cursor, dinv, h2p);

    const int MT = NN / 16;          // 6250 M-tiles
    fc_kernel<<<(MT + 3) / 4, 256, 0, stream>>>(h2p, W, b, out, MT);
}